// Round 1
// baseline (3213.733 us; speedup 1.0000x reference)
//
#include <hip/hip_runtime.h>
#include <math.h>

#define V 100000
#define H 1280
#define E 300
#define L 32
#define G3 (3*H)          // 3840

// Workspace layout (float/int slots, 4B each)
#define WS_H      0                    // h[1280]
#define WS_EMB    1280                 // emb[300] (padded to 320)
#define WS_GI     1600                 // gi[3840]
#define WS_GH     (WS_GI + G3)         // gh[3840]
#define NPART     6250                 // 100000 / 16
#define WS_PVAL   (WS_GH + G3)         // partial argmax values [6250]
#define WS_PIDX   (WS_PVAL + NPART)    // partial argmax indices [6250]
#define WS_DONE   (WS_PIDX + NPART)    // int done flag

__global__ __launch_bounds__(256)
void init_state(const float* __restrict__ hidden0, const float* __restrict__ start_emb,
                float* __restrict__ ws) {
    int i = blockIdx.x * blockDim.x + threadIdx.x;
    if (i < H) ws[WS_H + i] = hidden0[i];
    if (i < E) ws[WS_EMB + i] = start_emb[i];
    if (i == 0) ((int*)ws)[WS_DONE] = 0;
}

// One wave per row of the 3*H gate matrix; fused W_ih@emb and W_hh@h dots.
__global__ __launch_bounds__(256)
void gru_matvec(const float* __restrict__ W_ih, const float* __restrict__ W_hh,
                const float* __restrict__ b_ih, const float* __restrict__ b_hh,
                float* __restrict__ ws) {
    const int wave = threadIdx.x >> 6;
    const int lane = threadIdx.x & 63;
    const int row = blockIdx.x * 4 + wave;   // < 3840

    const float4* __restrict__ emb4 = (const float4*)(ws + WS_EMB);
    const float4* __restrict__ h4   = (const float4*)(ws + WS_H);

    // W_ih row: 300 floats = 75 float4
    const float4* __restrict__ wi = (const float4*)(W_ih + (size_t)row * E);
    float s1 = 0.f;
    for (int i = lane; i < 75; i += 64) {
        float4 w = wi[i], e = emb4[i];
        s1 += w.x*e.x + w.y*e.y + w.z*e.z + w.w*e.w;
    }
    // W_hh row: 1280 floats = 320 float4
    const float4* __restrict__ wh = (const float4*)(W_hh + (size_t)row * H);
    float s2 = 0.f;
    #pragma unroll
    for (int k = 0; k < 5; ++k) {
        float4 w = wh[lane + 64*k], hv = h4[lane + 64*k];
        s2 += w.x*hv.x + w.y*hv.y + w.z*hv.z + w.w*hv.w;
    }
    #pragma unroll
    for (int off = 32; off; off >>= 1) {
        s1 += __shfl_down(s1, off);
        s2 += __shfl_down(s2, off);
    }
    if (lane == 0) {
        ws[WS_GI + row] = s1 + b_ih[row];
        ws[WS_GH + row] = s2 + b_hh[row];
    }
}

// Gates + h update (done-masked) + store hiddens[t]
__global__ __launch_bounds__(256)
void gru_combine(float* __restrict__ ws, float* __restrict__ hid_out) {
    int j = blockIdx.x * blockDim.x + threadIdx.x;
    if (j >= H) return;
    int done = ((const int*)ws)[WS_DONE];
    float gir = ws[WS_GI + j], giz = ws[WS_GI + H + j], gin = ws[WS_GI + 2*H + j];
    float ghr = ws[WS_GH + j], ghz = ws[WS_GH + H + j], ghn = ws[WS_GH + 2*H + j];
    float r = 1.f / (1.f + expf(-(gir + ghr)));
    float z = 1.f / (1.f + expf(-(giz + ghz)));
    float n = tanhf(gin + r * ghn);
    float hold = ws[WS_H + j];
    float hnew = done ? hold : (1.f - z) * n + z * hold;
    ws[WS_H + j] = hnew;
    hid_out[j] = hnew;
}

// Classifier GEMV: 16 rows/block (4 waves x 4 rows), block-level argmax partial.
// Tie-break: first (lowest) index, matching jnp.argmax.
__global__ __launch_bounds__(256)
void logits_argmax_partial(const float* __restrict__ W_cls,
                           const float* __restrict__ b_cls,
                           float* __restrict__ ws) {
    const int wave = threadIdx.x >> 6;
    const int lane = threadIdx.x & 63;
    const int row0 = blockIdx.x * 16 + wave * 4;
    const float4* __restrict__ h4 = (const float4*)(ws + WS_H);

    float best = -INFINITY;
    int bidx = 0x7fffffff;
    for (int rr = 0; rr < 4; ++rr) {
        const int row = row0 + rr;
        const float4* __restrict__ wr = (const float4*)(W_cls + (size_t)row * H);
        float s = 0.f;
        #pragma unroll
        for (int k = 0; k < 5; ++k) {
            float4 w = wr[lane + 64*k], hv = h4[lane + 64*k];
            s += w.x*hv.x + w.y*hv.y + w.z*hv.z + w.w*hv.w;
        }
        #pragma unroll
        for (int off = 32; off; off >>= 1) s += __shfl_down(s, off);
        if (lane == 0) {
            float logit = s + b_cls[row];
            if (logit > best) { best = logit; bidx = row; }  // ascending rr keeps first max
        }
    }
    __shared__ float sval[4];
    __shared__ int   sidx[4];
    if (lane == 0) { sval[wave] = best; sidx[wave] = bidx; }
    __syncthreads();
    if (threadIdx.x == 0) {
        float bv = sval[0]; int bi = sidx[0];
        #pragma unroll
        for (int w = 1; w < 4; ++w) {
            if (sval[w] > bv || (sval[w] == bv && sidx[w] < bi)) { bv = sval[w]; bi = sidx[w]; }
        }
        ws[WS_PVAL + blockIdx.x] = bv;
        ((int*)ws)[WS_PIDX + blockIdx.x] = bi;
    }
}

// Final argmax over partials + token/done update + embedding gather.
__global__ __launch_bounds__(1024)
void argmax_update(float* __restrict__ ws, const float* __restrict__ vocab,
                   float* __restrict__ tok_out, int t) {
    __shared__ float sval[1024];
    __shared__ int   sidx[1024];
    const int tid = threadIdx.x;
    float best = -INFINITY;
    int bidx = 0x7fffffff;
    for (int i = tid; i < NPART; i += 1024) {
        float v = ws[WS_PVAL + i];
        int  id = ((const int*)ws)[WS_PIDX + i];
        if (v > best || (v == best && id < bidx)) { best = v; bidx = id; }
    }
    sval[tid] = best; sidx[tid] = bidx;
    __syncthreads();
    #pragma unroll
    for (int s = 512; s; s >>= 1) {
        if (tid < s) {
            if (sval[tid+s] > sval[tid] ||
                (sval[tid+s] == sval[tid] && sidx[tid+s] < sidx[tid])) {
                sval[tid] = sval[tid+s]; sidx[tid] = sidx[tid+s];
            }
        }
        __syncthreads();
    }
    __shared__ int s_pred, s_donenew;
    if (tid == 0) {
        int pred = sidx[0];
        int done = ((const int*)ws)[WS_DONE];
        int token = done ? 0 : pred;
        tok_out[t] = (float)token;
        int done_new = done | (pred == 0);
        ((int*)ws)[WS_DONE] = done_new;
        s_pred = pred; s_donenew = done_new;
    }
    __syncthreads();
    if (!s_donenew && tid < E) {
        ws[WS_EMB + tid] = vocab[(size_t)s_pred * E + tid];
    }
}

extern "C" void kernel_launch(void* const* d_in, const int* in_sizes, int n_in,
                              void* d_out, int out_size, void* d_ws, size_t ws_size,
                              hipStream_t stream) {
    const float* hidden0   = (const float*)d_in[0];
    const float* start_emb = (const float*)d_in[1];
    const float* W_ih      = (const float*)d_in[2];
    const float* W_hh      = (const float*)d_in[3];
    const float* b_ih      = (const float*)d_in[4];
    const float* b_hh      = (const float*)d_in[5];
    const float* W_cls     = (const float*)d_in[6];
    const float* b_cls     = (const float*)d_in[7];
    const float* vocab     = (const float*)d_in[8];
    float* out = (float*)d_out;
    float* ws  = (float*)d_ws;

    hipLaunchKernelGGL(init_state, dim3(5), dim3(256), 0, stream, hidden0, start_emb, ws);
    for (int t = 0; t < L; ++t) {
        hipLaunchKernelGGL(gru_matvec, dim3(G3/4), dim3(256), 0, stream,
                           W_ih, W_hh, b_ih, b_hh, ws);
        hipLaunchKernelGGL(gru_combine, dim3(5), dim3(256), 0, stream,
                           ws, out + L + (size_t)t * H);
        hipLaunchKernelGGL(logits_argmax_partial, dim3(NPART), dim3(256), 0, stream,
                           W_cls, b_cls, ws);
        hipLaunchKernelGGL(argmax_update, dim3(1), dim3(1024), 0, stream,
                           ws, vocab, out, t);
    }
}

// Round 2
// 2175.138 us; speedup vs baseline: 1.4775x; 1.4775x over previous
//
#include <hip/hip_runtime.h>
#include <math.h>
#include <limits.h>

#define V 100000
#define H 1280
#define E 300
#define L 32
#define G3 (3*H)          // 3840

// Workspace layout (float/int slots, 4B each)
#define WS_H      0                    // h[1280]
#define WS_EMB    1280                 // emb[300] (padded to 320)
#define WS_GI     1600                 // gi[3840]
#define WS_GH     (WS_GI + G3)         // gh[3840]
#define NPART     6250                 // 100000 / 16 rows per block
#define WS_PV1    (WS_GH + G3)         // block top-1 value [6250]
#define WS_PV2    (WS_PV1 + NPART)     // block top-2 value [6250]
#define WS_PI1    (WS_PV2 + NPART)     // block top-1 index [6250]
#define WS_PI2    (WS_PI1 + NPART)     // block top-2 index [6250]
#define WS_PB     (WS_PI2 + NPART)     // block max error bound [6250]
#define WS_DONE   (WS_PB + NPART)      // int done flag
// bf16 copy of W_cls starts at byte offset 164000 (8B aligned)
#define WS_BF16_BYTEOFF 164000
#define WS_BYTES_NEEDED (WS_BF16_BYTEOFF + (size_t)V * H * 2)

// legacy fp32-fallback partial arrays (reuse PV1/PI1 slots)
#define WS_PVAL   WS_PV1
#define WS_PIDX   WS_PI1

__global__ __launch_bounds__(256)
void init_state(const float* __restrict__ hidden0, const float* __restrict__ start_emb,
                float* __restrict__ ws) {
    int i = blockIdx.x * blockDim.x + threadIdx.x;
    if (i < H) ws[WS_H + i] = hidden0[i];
    if (i < E) ws[WS_EMB + i] = start_emb[i];
    if (i == 0) ((int*)ws)[WS_DONE] = 0;
}

// fp32 -> bf16 (round-to-nearest-even), 4 elems/thread/iter, grid-stride.
__global__ __launch_bounds__(256)
void convert_wcls(const float* __restrict__ W, ushort* __restrict__ out) {
    const size_t total4 = (size_t)V * H / 4;   // 32,000,000 float4s
    size_t stride = (size_t)gridDim.x * blockDim.x;
    for (size_t i = blockIdx.x * (size_t)blockDim.x + threadIdx.x; i < total4; i += stride) {
        float4 v = ((const float4*)W)[i];
        ushort4 r;
        uint b;
        b = __float_as_uint(v.x); r.x = (ushort)((b + 0x7fffu + ((b >> 16) & 1u)) >> 16);
        b = __float_as_uint(v.y); r.y = (ushort)((b + 0x7fffu + ((b >> 16) & 1u)) >> 16);
        b = __float_as_uint(v.z); r.z = (ushort)((b + 0x7fffu + ((b >> 16) & 1u)) >> 16);
        b = __float_as_uint(v.w); r.w = (ushort)((b + 0x7fffu + ((b >> 16) & 1u)) >> 16);
        ((ushort4*)out)[i] = r;
    }
}

// One wave per row of the 3*H gate matrix; fused W_ih@emb and W_hh@h dots.
__global__ __launch_bounds__(256)
void gru_matvec(const float* __restrict__ W_ih, const float* __restrict__ W_hh,
                const float* __restrict__ b_ih, const float* __restrict__ b_hh,
                float* __restrict__ ws) {
    const int wave = threadIdx.x >> 6;
    const int lane = threadIdx.x & 63;
    const int row = blockIdx.x * 4 + wave;   // < 3840

    const float4* __restrict__ emb4 = (const float4*)(ws + WS_EMB);
    const float4* __restrict__ h4   = (const float4*)(ws + WS_H);

    const float4* __restrict__ wi = (const float4*)(W_ih + (size_t)row * E);
    float s1 = 0.f;
    for (int i = lane; i < 75; i += 64) {
        float4 w = wi[i], e = emb4[i];
        s1 += w.x*e.x + w.y*e.y + w.z*e.z + w.w*e.w;
    }
    const float4* __restrict__ wh = (const float4*)(W_hh + (size_t)row * H);
    float s2 = 0.f;
    #pragma unroll
    for (int k = 0; k < 5; ++k) {
        float4 w = wh[lane + 64*k], hv = h4[lane + 64*k];
        s2 += w.x*hv.x + w.y*hv.y + w.z*hv.z + w.w*hv.w;
    }
    #pragma unroll
    for (int off = 32; off; off >>= 1) {
        s1 += __shfl_down(s1, off);
        s2 += __shfl_down(s2, off);
    }
    if (lane == 0) {
        ws[WS_GI + row] = s1 + b_ih[row];
        ws[WS_GH + row] = s2 + b_hh[row];
    }
}

// Gates + h update (done-masked) + store hiddens[t]
__global__ __launch_bounds__(256)
void gru_combine(float* __restrict__ ws, float* __restrict__ hid_out) {
    int j = blockIdx.x * blockDim.x + threadIdx.x;
    if (j >= H) return;
    int done = ((const int*)ws)[WS_DONE];
    float gir = ws[WS_GI + j], giz = ws[WS_GI + H + j], gin = ws[WS_GI + 2*H + j];
    float ghr = ws[WS_GH + j], ghz = ws[WS_GH + H + j], ghn = ws[WS_GH + 2*H + j];
    float r = 1.f / (1.f + expf(-(gir + ghr)));
    float z = 1.f / (1.f + expf(-(giz + ghz)));
    float n = tanhf(gin + r * ghn);
    float hold = ws[WS_H + j];
    float hnew = done ? hold : (1.f - z) * n + z * hold;
    ws[WS_H + j] = hnew;
    hid_out[j] = hnew;
}

// bf16 classifier GEMV: 16 rows/block (4 waves x 4 rows). Each row also
// accumulates sabs = sum|w*h| for a rigorous quantization error bound.
// Block forwards top-2 (value,idx) + max bound.
__global__ __launch_bounds__(256)
void cls_bf16_partial(const ushort* __restrict__ Wb,
                      const float* __restrict__ b_cls,
                      float* __restrict__ ws) {
    const int wave = threadIdx.x >> 6;
    const int lane = threadIdx.x & 63;
    const int row0 = blockIdx.x * 16 + wave * 4;
    const float4* __restrict__ h4 = (const float4*)(ws + WS_H);

    float v1 = -INFINITY, v2 = -INFINITY, bmax = 0.f;
    int i1 = INT_MAX, i2 = INT_MAX;

    for (int rr = 0; rr < 4; ++rr) {
        const int row = row0 + rr;
        const ushort4* __restrict__ wr = (const ushort4*)(Wb + (size_t)row * H);
        float s = 0.f, sa = 0.f;
        #pragma unroll
        for (int k = 0; k < 5; ++k) {
            ushort4 u = wr[lane + 64*k];
            float4 hv = h4[lane + 64*k];
            float w0 = __uint_as_float((uint)u.x << 16);
            float w1 = __uint_as_float((uint)u.y << 16);
            float w2 = __uint_as_float((uint)u.z << 16);
            float w3 = __uint_as_float((uint)u.w << 16);
            s += w0*hv.x + w1*hv.y + w2*hv.z + w3*hv.w;
            sa += fabsf(w0*hv.x) + fabsf(w1*hv.y) + fabsf(w2*hv.z) + fabsf(w3*hv.w);
        }
        #pragma unroll
        for (int off = 32; off; off >>= 1) {
            s  += __shfl_down(s, off);
            sa += __shfl_down(sa, off);
        }
        if (lane == 0) {
            float logit = s + b_cls[row];
            // |bf16 logit - fp32 logit| <= 2^-8 * sum|w*h| * (1+eps) + accum slop
            float e = 0.004f * sa + 1e-5f;
            bmax = fmaxf(bmax, e);
            if (logit > v1 || (logit == v1 && row < i1)) {
                v2 = v1; i2 = i1; v1 = logit; i1 = row;
            } else if (logit > v2 || (logit == v2 && row < i2)) {
                v2 = logit; i2 = row;
            }
        }
    }
    __shared__ float sv1[4], sv2[4], sb[4];
    __shared__ int   si1[4], si2[4];
    if (lane == 0) { sv1[wave]=v1; sv2[wave]=v2; si1[wave]=i1; si2[wave]=i2; sb[wave]=bmax; }
    __syncthreads();
    if (threadIdx.x == 0) {
        float bv1=-INFINITY, bv2=-INFINITY, bb=0.f;
        int bi1=INT_MAX, bi2=INT_MAX;
        #pragma unroll
        for (int w = 0; w < 4; ++w) {
            bb = fmaxf(bb, sb[w]);
            float vv[2] = { sv1[w], sv2[w] };
            int   ii[2] = { si1[w], si2[w] };
            #pragma unroll
            for (int q = 0; q < 2; ++q) {
                float v = vv[q]; int i = ii[q];
                if (v > bv1 || (v == bv1 && i < bi1)) {
                    bv2 = bv1; bi2 = bi1; bv1 = v; bi1 = i;
                } else if (v > bv2 || (v == bv2 && i < bi2)) {
                    bv2 = v; bi2 = i;
                }
            }
        }
        ws[WS_PV1 + blockIdx.x] = bv1;
        ws[WS_PV2 + blockIdx.x] = bv2;
        ((int*)ws)[WS_PI1 + blockIdx.x] = bi1;
        ((int*)ws)[WS_PI2 + blockIdx.x] = bi2;
        ws[WS_PB + blockIdx.x] = bb;
    }
}

// Single-block finalize: global max of (v-e), candidate select (v+e >= m),
// exact fp32 rescore of candidates from original W_cls, argmax with
// first-index tie-break, token/done/embedding update.
__global__ __launch_bounds__(1024)
void finalize(float* __restrict__ ws, const float* __restrict__ W_cls,
              const float* __restrict__ b_cls, const float* __restrict__ vocab,
              float* __restrict__ tok_out, int t) {
    __shared__ float red[1024];
    __shared__ int cnt;
    __shared__ int cidx[64];
    __shared__ float cval[64];
    __shared__ int s_pred, s_done_new;
    const int tid = threadIdx.x;

    // pass 1: m = max(v1 - bound)
    float m = -INFINITY;
    for (int e = tid; e < NPART; e += 1024)
        m = fmaxf(m, ws[WS_PV1 + e] - ws[WS_PB + e]);
    red[tid] = m;
    __syncthreads();
    for (int s = 512; s; s >>= 1) {
        if (tid < s) red[tid] = fmaxf(red[tid], red[tid + s]);
        __syncthreads();
    }
    m = red[0];
    if (tid == 0) cnt = 0;
    __syncthreads();

    // pass 2: collect candidates with v + bound >= m
    for (int e = tid; e < NPART; e += 1024) {
        float b = ws[WS_PB + e];
        float v1 = ws[WS_PV1 + e];
        if (v1 + b >= m) {
            int p = atomicAdd(&cnt, 1);
            if (p < 64) cidx[p] = ((const int*)ws)[WS_PI1 + e];
        }
        float v2 = ws[WS_PV2 + e];
        if (v2 + b >= m) {
            int p = atomicAdd(&cnt, 1);
            if (p < 64) cidx[p] = ((const int*)ws)[WS_PI2 + e];
        }
    }
    __syncthreads();
    int nc = min(cnt, 64);

    // exact fp32 rescore of each candidate row
    const float* __restrict__ h = ws + WS_H;
    for (int c = 0; c < nc; ++c) {
        int row = cidx[c];
        const float* __restrict__ wr = W_cls + (size_t)row * H;
        float p = 0.f;
        if (tid < H) p = wr[tid] * h[tid];
        int j = tid + 1024;
        if (j < H) p += wr[j] * h[j];
        red[tid] = p;
        __syncthreads();
        for (int s = 512; s; s >>= 1) {
            if (tid < s) red[tid] += red[tid + s];
            __syncthreads();
        }
        if (tid == 0) cval[c] = red[0] + b_cls[row];
        __syncthreads();
    }

    if (tid == 0) {
        float bv = -INFINITY; int bi = INT_MAX;
        for (int c = 0; c < nc; ++c) {
            float v = cval[c]; int i = cidx[c];
            if (v > bv || (v == bv && i < bi)) { bv = v; bi = i; }
        }
        int done = ((const int*)ws)[WS_DONE];
        int pred = bi;
        tok_out[t] = (float)(done ? 0 : pred);
        int dn = done | (pred == 0);
        ((int*)ws)[WS_DONE] = dn;
        s_pred = pred; s_done_new = dn;
    }
    __syncthreads();
    if (!s_done_new && tid < E)
        ws[WS_EMB + tid] = vocab[(size_t)s_pred * E + tid];
}

// ---------- fp32 fallback path (proven in R0) ----------
__global__ __launch_bounds__(256)
void logits_argmax_partial(const float* __restrict__ W_cls,
                           const float* __restrict__ b_cls,
                           float* __restrict__ ws) {
    const int wave = threadIdx.x >> 6;
    const int lane = threadIdx.x & 63;
    const int row0 = blockIdx.x * 16 + wave * 4;
    const float4* __restrict__ h4 = (const float4*)(ws + WS_H);

    float best = -INFINITY;
    int bidx = INT_MAX;
    for (int rr = 0; rr < 4; ++rr) {
        const int row = row0 + rr;
        const float4* __restrict__ wr = (const float4*)(W_cls + (size_t)row * H);
        float s = 0.f;
        #pragma unroll
        for (int k = 0; k < 5; ++k) {
            float4 w = wr[lane + 64*k], hv = h4[lane + 64*k];
            s += w.x*hv.x + w.y*hv.y + w.z*hv.z + w.w*hv.w;
        }
        #pragma unroll
        for (int off = 32; off; off >>= 1) s += __shfl_down(s, off);
        if (lane == 0) {
            float logit = s + b_cls[row];
            if (logit > best) { best = logit; bidx = row; }
        }
    }
    __shared__ float sval[4];
    __shared__ int   sidx[4];
    if (lane == 0) { sval[wave] = best; sidx[wave] = bidx; }
    __syncthreads();
    if (threadIdx.x == 0) {
        float bv = sval[0]; int bi = sidx[0];
        #pragma unroll
        for (int w = 1; w < 4; ++w) {
            if (sval[w] > bv || (sval[w] == bv && sidx[w] < bi)) { bv = sval[w]; bi = sidx[w]; }
        }
        ws[WS_PVAL + blockIdx.x] = bv;
        ((int*)ws)[WS_PIDX + blockIdx.x] = bi;
    }
}

__global__ __launch_bounds__(1024)
void argmax_update(float* __restrict__ ws, const float* __restrict__ vocab,
                   float* __restrict__ tok_out, int t) {
    __shared__ float sval[1024];
    __shared__ int   sidx[1024];
    const int tid = threadIdx.x;
    float best = -INFINITY;
    int bidx = INT_MAX;
    for (int i = tid; i < NPART; i += 1024) {
        float v = ws[WS_PVAL + i];
        int  id = ((const int*)ws)[WS_PIDX + i];
        if (v > best || (v == best && id < bidx)) { best = v; bidx = id; }
    }
    sval[tid] = best; sidx[tid] = bidx;
    __syncthreads();
    #pragma unroll
    for (int s = 512; s; s >>= 1) {
        if (tid < s) {
            if (sval[tid+s] > sval[tid] ||
                (sval[tid+s] == sval[tid] && sidx[tid+s] < sidx[tid])) {
                sval[tid] = sval[tid+s]; sidx[tid] = sidx[tid+s];
            }
        }
        __syncthreads();
    }
    __shared__ int s_pred, s_donenew;
    if (tid == 0) {
        int pred = sidx[0];
        int done = ((const int*)ws)[WS_DONE];
        tok_out[t] = (float)(done ? 0 : pred);
        int done_new = done | (pred == 0);
        ((int*)ws)[WS_DONE] = done_new;
        s_pred = pred; s_donenew = done_new;
    }
    __syncthreads();
    if (!s_donenew && tid < E) {
        ws[WS_EMB + tid] = vocab[(size_t)s_pred * E + tid];
    }
}

extern "C" void kernel_launch(void* const* d_in, const int* in_sizes, int n_in,
                              void* d_out, int out_size, void* d_ws, size_t ws_size,
                              hipStream_t stream) {
    const float* hidden0   = (const float*)d_in[0];
    const float* start_emb = (const float*)d_in[1];
    const float* W_ih      = (const float*)d_in[2];
    const float* W_hh      = (const float*)d_in[3];
    const float* b_ih      = (const float*)d_in[4];
    const float* b_hh      = (const float*)d_in[5];
    const float* W_cls     = (const float*)d_in[6];
    const float* b_cls     = (const float*)d_in[7];
    const float* vocab     = (const float*)d_in[8];
    float* out = (float*)d_out;
    float* ws  = (float*)d_ws;

    hipLaunchKernelGGL(init_state, dim3(5), dim3(256), 0, stream, hidden0, start_emb, ws);

    if (ws_size >= WS_BYTES_NEEDED) {
        ushort* Wb = (ushort*)((char*)d_ws + WS_BF16_BYTEOFF);
        hipLaunchKernelGGL(convert_wcls, dim3(4096), dim3(256), 0, stream, W_cls, Wb);
        for (int t = 0; t < L; ++t) {
            hipLaunchKernelGGL(gru_matvec, dim3(G3/4), dim3(256), 0, stream,
                               W_ih, W_hh, b_ih, b_hh, ws);
            hipLaunchKernelGGL(gru_combine, dim3(5), dim3(256), 0, stream,
                               ws, out + L + (size_t)t * H);
            hipLaunchKernelGGL(cls_bf16_partial, dim3(NPART), dim3(256), 0, stream,
                               Wb, b_cls, ws);
            hipLaunchKernelGGL(finalize, dim3(1), dim3(1024), 0, stream,
                               ws, W_cls, b_cls, vocab, out, t);
        }
    } else {
        for (int t = 0; t < L; ++t) {
            hipLaunchKernelGGL(gru_matvec, dim3(G3/4), dim3(256), 0, stream,
                               W_ih, W_hh, b_ih, b_hh, ws);
            hipLaunchKernelGGL(gru_combine, dim3(5), dim3(256), 0, stream,
                               ws, out + L + (size_t)t * H);
            hipLaunchKernelGGL(logits_argmax_partial, dim3(NPART), dim3(256), 0, stream,
                               W_cls, b_cls, ws);
            hipLaunchKernelGGL(argmax_update, dim3(1), dim3(1024), 0, stream,
                               ws, vocab, out, t);
        }
    }
}